// Round 6
// baseline (2333.742 us; speedup 1.0000x reference)
//
#include <hip/hip_runtime.h>

// R9 -> R10: R9 confirmed the LDS-atomic law (atomic-free n_accum left the
// top-5; accum 556 -> <300us) but n_scatter blew up: 805MB WRITE for a
// 205MB array. Cause: 12500 open write streams x ~96 blocks/XCD >> 4MB L2
// -> partial-line evict/refetch/rewrite. Locality law: open streams/XCD
// must fit L2. Fix:
//   - coarse sort to 256-atom bins (782 bins; 256 blocks x 782 streams =
//     1.6MB/XCD -> write-combining restored).
//   - f_accum fuses the fine routing: per coarse bin, batches of 256
//     tuples staged in ping-pong LDS; thread (f,s) consumes staged tuples
//     at positions j==s (mod 16) whose fine bin == f -> exactly one
//     consumer per tuple, R9 conflict-free private slots, ZERO atomics,
//     no second global sort, direct coalesced out write.

#define NCH    256          // edge chunks for hist/scatter
#define TB     1024         // hist/scatter block size
#define CBLOG  8
#define CBSZ   256          // atoms per coarse bin
#define MAXCB  1024         // LDS hist/cursor capacity

static __device__ __forceinline__ unsigned long long nt_u64(const void* p) {
    return __builtin_nontemporal_load((const unsigned long long*)p);
}
static __device__ __forceinline__ float nt_f32(const float* p) {
    return __builtin_nontemporal_load(p);
}
static __device__ __forceinline__ void nt_st_u64(unsigned long long v, void* p) {
    __builtin_nontemporal_store(v, (unsigned long long*)p);
}

// ---- C1: per-chunk histogram over 256-atom coarse bins ------------------
__global__ __launch_bounds__(TB) void c_hist(
    const int2* __restrict__ nbr, int* __restrict__ chist,
    int n_edges, int nbins)
{
    __shared__ int h[MAXCB];
    for (int i = threadIdx.x; i < nbins; i += TB) h[i] = 0;
    __syncthreads();
    int per = (n_edges + NCH - 1) / NCH;
    int lo = blockIdx.x * per;
    int hi = min(lo + per, n_edges);
    #pragma unroll 2
    for (int e = lo + threadIdx.x; e < hi; e += TB) {
        unsigned long long v = nt_u64(&nbr[e]);
        int ix = (int)(v & 0xffffffffu);
        int iy = (int)(v >> 32);
        atomicAdd(&h[ix >> CBLOG], 1);
        atomicAdd(&h[iy >> CBLOG], 1);
    }
    __syncthreads();
    int* out = chist + (size_t)blockIdx.x * nbins;
    for (int i = threadIdx.x; i < nbins; i += TB) out[i] = h[i];
}

// ---- C2: scan each bin's NCH chunk-counts -------------------------------
__global__ __launch_bounds__(NCH) void c_rowscan(
    const int* __restrict__ chist, int* __restrict__ coffs,
    int* __restrict__ ctot, int nbins)
{
    __shared__ int a[NCH];
    int bin = blockIdx.x, t = threadIdx.x;
    int v = chist[(size_t)t * nbins + bin];
    a[t] = v;
    __syncthreads();
    for (int off = 1; off < NCH; off <<= 1) {
        int x = (t >= off) ? a[t - off] : 0;
        __syncthreads();
        a[t] += x;
        __syncthreads();
    }
    coffs[(size_t)t * nbins + bin] = a[t] - v;
    if (t == NCH - 1) ctot[bin] = a[t];
}

// ---- C3: exclusive scan of bin totals (one block; nbins <= 1024) --------
__global__ __launch_bounds__(1024) void c_bases(
    const int* __restrict__ ctot, int* __restrict__ cbase, int nbins)
{
    __shared__ int sums[1024];
    int t = threadIdx.x;
    int v = (t < nbins) ? ctot[t] : 0;
    sums[t] = v;
    __syncthreads();
    for (int off = 1; off < 1024; off <<= 1) {
        int x = (t >= off) ? sums[t - off] : 0;
        __syncthreads();
        sums[t] += x;
        __syncthreads();
    }
    if (t < nbins) cbase[t] = sums[t] - v;
}

// ---- C4: coffs[chunk][bin] += cbase[bin] --------------------------------
__global__ __launch_bounds__(1024) void c_addbase(
    int* __restrict__ coffs, const int* __restrict__ cbase, int nbins)
{
    int bin = threadIdx.x;
    if (bin < nbins)
        coffs[(size_t)blockIdx.y * nbins + bin] += cbase[bin];
}

// ---- C5: scatter TWO tuples per edge into coarse bins -------------------
// tuple.x = dst_local(8b) | src_global(18b)<<8 ; tuple.y = w bits
__global__ __launch_bounds__(TB) void c_scatter(
    const int2* __restrict__ nbr, const float* __restrict__ dist,
    const int* __restrict__ coffs, uint2* __restrict__ tuples,
    int n_edges, int nbins)
{
    __shared__ int cur[MAXCB];
    const int* src = coffs + (size_t)blockIdx.x * nbins;
    for (int i = threadIdx.x; i < nbins; i += TB) cur[i] = src[i];
    __syncthreads();
    int per = (n_edges + NCH - 1) / NCH;
    int lo = blockIdx.x * per;
    int hi = min(lo + per, n_edges);
    #pragma unroll 2
    for (int e = lo + threadIdx.x; e < hi; e += TB) {
        unsigned long long v = nt_u64(&nbr[e]);
        int ix = (int)(v & 0xffffffffu);
        int iy = (int)(v >> 32);
        float w = 0.5f / nt_f32(&dist[e]);
        unsigned wb = __float_as_uint(w);
        int pi = atomicAdd(&cur[ix >> CBLOG], 1);
        nt_st_u64((unsigned long long)((unsigned)(ix & (CBSZ - 1)) | ((unsigned)iy << CBLOG))
                  | ((unsigned long long)wb << 32), &tuples[pi]);
        int pj = atomicAdd(&cur[iy >> CBLOG], 1);
        nt_st_u64((unsigned long long)((unsigned)(iy & (CBSZ - 1)) | ((unsigned)ix << CBLOG))
                  | ((unsigned long long)wb << 32), &tuples[pj]);
    }
}

// ---- C6: fused fine-routing accumulation (atomic-free) ------------------
// block = coarse bin b (256 atoms), 256 thr. thread t: fine bin f=t>>4
// (atoms f*16..f*16+15 local), slice s=t&15. Batch of 256 tuples staged in
// LDS; thread consumes staged[j] for j==s (mod 16) when fine(j)==f.
// Private slots accv[d*256+t] (stride 4096B: conflict-free).
__global__ __launch_bounds__(256) void f_accum(
    const uint2* __restrict__ tuples, const float4* __restrict__ charges,
    const int* __restrict__ cbase, const int* __restrict__ ctot,
    float4* __restrict__ out, int n_atoms)
{
    __shared__ float4 accv[16 * 256];    // 64 KB
    __shared__ uint2  stg[2][256];       // 4 KB ping-pong
    int tid = threadIdx.x;
    int b = blockIdx.x;
    float4 z = make_float4(0.f, 0.f, 0.f, 0.f);
    #pragma unroll
    for (int d = 0; d < 16; ++d) accv[d * 256 + tid] = z;

    int lo = cbase[b], cnt = ctot[b];
    int f = tid >> 4;
    int s = tid & 15;
    int nbatch = (cnt + 255) >> 8;

    uint2 nxt = make_uint2(0u, 0u);
    if (tid < cnt) {
        unsigned long long t0 = nt_u64(&tuples[lo + tid]);
        nxt = make_uint2((unsigned)t0, (unsigned)(t0 >> 32));
    }
    stg[0][tid] = nxt;
    __syncthreads();

    for (int bt = 0; bt < nbatch; ++bt) {
        bool more = (bt + 1 < nbatch);
        if (more) {
            int base = (bt + 1) << 8;
            int rem = cnt - base;
            nxt = make_uint2(0u, 0u);
            if (tid < rem) {
                unsigned long long t0 = nt_u64(&tuples[lo + base + tid]);
                nxt = make_uint2((unsigned)t0, (unsigned)(t0 >> 32));
            }
        }
        int cur_n = min(cnt - (bt << 8), 256);
        const uint2* S = stg[bt & 1];
        #pragma unroll
        for (int k = 0; k < 16; ++k) {
            int j = s + (k << 4);
            if (j < cur_n) {
                uint2 t = S[j];
                unsigned x = t.x;
                if (((x >> 4) & 15u) == (unsigned)f) {
                    float w = __uint_as_float(t.y);
                    float4 c = charges[x >> CBLOG];
                    int d = (int)(x & 15u);
                    float4 v = accv[d * 256 + tid];
                    v.x += c.x * w; v.y += c.y * w;
                    v.z += c.z * w; v.w += c.w * w;
                    accv[d * 256 + tid] = v;
                }
            }
        }
        if (more) stg[(bt + 1) & 1][tid] = nxt;
        __syncthreads();
    }

    // reduce 16 slice copies; atom local index == tid -> coalesced store
    int a = (b << CBLOG) + tid;
    if (a < n_atoms) {
        int fb = tid >> 4, d = tid & 15;
        float4 r = z;
        #pragma unroll
        for (int s2 = 0; s2 < 16; ++s2) {
            float4 v = accv[d * 256 + fb * 16 + s2];
            r.x += v.x; r.y += v.y; r.z += v.z; r.w += v.w;
        }
        out[a] = r;
    }
}

// ---- fallback: agent-scope atomics --------------------------------------
__global__ __launch_bounds__(256) void edge_scatter_agent(
    const float4* __restrict__ charges, const int2* __restrict__ nbr,
    const float* __restrict__ dist, float* __restrict__ out, int n_edges)
{
    int e = blockIdx.x * blockDim.x + threadIdx.x;
    if (e >= n_edges) return;
    int2 ij = nbr[e];
    float w = 0.5f / dist[e];
    float4 cj = charges[ij.y];
    float4 ci = charges[ij.x];
    float* oi = out + (size_t)ij.x * 4;
    float* oj = out + (size_t)ij.y * 4;
    atomicAdd(oi + 0, cj.x * w); atomicAdd(oi + 1, cj.y * w);
    atomicAdd(oi + 2, cj.z * w); atomicAdd(oi + 3, cj.w * w);
    atomicAdd(oj + 0, ci.x * w); atomicAdd(oj + 1, ci.y * w);
    atomicAdd(oj + 2, ci.z * w); atomicAdd(oj + 3, ci.w * w);
}

// ============================== launcher =================================

extern "C" void kernel_launch(void* const* d_in, const int* in_sizes, int n_in,
                              void* d_out, int out_size, void* d_ws, size_t ws_size,
                              hipStream_t stream)
{
    const float4* charges = (const float4*)d_in[0];
    const int2*   nbr     = (const int2*)d_in[3];
    const float*  dist    = (const float*)d_in[4];

    int n_edges = in_sizes[4];
    int n_atoms = out_size / 4;
    int nbins   = (n_atoms + CBSZ - 1) >> CBLOG;   // 782 for 200000 atoms

    char* w = (char*)d_ws;
    auto align256 = [](size_t x) { return (x + 255) & ~(size_t)255; };

    size_t n_tup = (size_t)2 * n_edges;
    size_t szT = n_tup * sizeof(uint2);                  // ~205 MB
    size_t szH = (size_t)NCH * nbins * sizeof(int);      // ~0.8 MB

    size_t off = 0;
    size_t oT  = off; off += align256(szT);
    size_t oCH = off; off += align256(szH);
    size_t oCO = off; off += align256(szH);
    size_t oCT = off; off += align256((size_t)nbins * sizeof(int));
    size_t oCB = off; off += align256((size_t)nbins * sizeof(int));
    bool ok = (off <= ws_size) && (nbins <= MAXCB) && (n_atoms < (1 << 18));

    if (ok) {
        uint2* tuples = (uint2*)(w + oT);
        int*   chist  = (int*)(w + oCH);
        int*   coffs  = (int*)(w + oCO);
        int*   ctot   = (int*)(w + oCT);
        int*   cbase  = (int*)(w + oCB);

        c_hist   <<<NCH, TB, 0, stream>>>(nbr, chist, n_edges, nbins);
        c_rowscan<<<nbins, NCH, 0, stream>>>(chist, coffs, ctot, nbins);
        c_bases  <<<1, 1024, 0, stream>>>(ctot, cbase, nbins);
        {
            dim3 g(1, NCH);
            c_addbase<<<g, 1024, 0, stream>>>(coffs, cbase, nbins);
        }
        c_scatter<<<NCH, TB, 0, stream>>>(nbr, dist, coffs, tuples,
                                          n_edges, nbins);
        f_accum  <<<nbins, 256, 0, stream>>>(tuples, charges, cbase, ctot,
                                             (float4*)d_out, n_atoms);
    } else {
        hipMemsetAsync(d_out, 0, (size_t)out_size * sizeof(float), stream);
        edge_scatter_agent<<<(n_edges + 255) / 256, 256, 0, stream>>>(
            charges, nbr, dist, (float*)d_out, n_edges);
    }
}